// Round 1
// 397.269 us; speedup vs baseline: 1.0563x; 1.0563x over previous
//
#include <hip/hip_runtime.h>
#include <cstdint>

#define D 128
#define NPTS 200000
#define KNN 50
#define CAP 8192
#define NS 8192
#define SLACK 2.0f
#define EB 2048

// ---- workspace byte offsets ----
#define OFF_ACC    0         // 32 f32 (zeroed)
#define OFF_SEL    256       // 16 u32 (zeroed)
#define OFF_CNT    1024      // 256*16 u32 (zeroed, 1 counter / 64B line)
#define OFF_HIST0  17408     // 4096*8 u32 sharded (zeroed)
#define OFF_HIST12 148480    // 2*2*4096 u32 (zeroed)
#define MEMSET_BYTES 214016
#define OFF_COMB   214016    // 512*128 f32
#define OFF_D2     476160    // 262144 f32
#define OFF_XN     1524736   // 200000 f32
#define OFF_SAMP   2324736   // 256*8192 f32
#define OFF_EBUF   2324736   // alias: 1024*2048 u32 block-local candidate lists (samp dead after k_h1thr)
#define OFF_THR    10713344  // 256 f32
#define OFF_CANDI  10714368  // 256*8192 i32
#define OFF_KSG    19102976  // 256*8192 u32 rescored keys
#define OFF_BCNT   19102976  // alias: 1024 u32 block counts (ksg written only after k_scat)
#define OFF_TQSW   27491584  // 256*128 bf16 swizzled
#define OFF_XBF    27557120  // 200000*128 bf16 swizzled (51.2 MB)

typedef __attribute__((ext_vector_type(8))) short bf16x8;
typedef __attribute__((ext_vector_type(4))) float f32x4;
typedef const __attribute__((address_space(1))) void* gas_p;
typedef __attribute__((address_space(3))) void* las_p;

__device__ __forceinline__ unsigned fkey(float f) {
    unsigned u = __float_as_uint(f);
    return u ^ ((unsigned)((int)u >> 31) | 0x80000000u);
}

// async-stage 8KB chunk (4096 ushorts) into LDS: wave-uniform lds base, lane*16B implicit
__device__ __forceinline__ void stage8k(const unsigned short* __restrict__ g,
                                        unsigned short* l, int w, int lane)
{
    #pragma unroll
    for (int j = 0; j < 2; j++) {
        const unsigned short* gp = g + j * 2048 + w * 512 + lane * 8;
        unsigned short* lp = l + j * 2048 + w * 512;
        __builtin_amdgcn_global_load_lds((gas_p)gp, (las_p)lp, 16, 0, 0);
    }
}

// ---- phase 1: X->bf16 swizzle + xnorm | Tq=qW^T+b (+swizzle, anchor) | comb X[idx] | W reg ----
__global__ void k_phase1(const float* __restrict__ q, const float* __restrict__ X,
                         const float* __restrict__ W, const float* __restrict__ bb,
                         const int* __restrict__ idx, float* __restrict__ comb,
                         unsigned short* __restrict__ tqsw, unsigned short* __restrict__ xbf,
                         float* __restrict__ xn, float* __restrict__ acc)
{
    const int blk = blockIdx.x, t = threadIdx.x;
    if (blk < 12500) {
        __shared__ float xr[16];
        const int lr = t & 15;
        if (t < 16) xr[t] = 0.f;
        __syncthreads();
        const float4* src = (const float4*)(X + ((long)(blk * 16 + lr)) * D + (t >> 4) * 8);
        float4 v0 = src[0], v1 = src[1];
        uint4 pk;
        pk.x = (__float_as_uint(v0.x) >> 16) | (__float_as_uint(v0.y) & 0xFFFF0000u);
        pk.y = (__float_as_uint(v0.z) >> 16) | (__float_as_uint(v0.w) & 0xFFFF0000u);
        pk.z = (__float_as_uint(v1.x) >> 16) | (__float_as_uint(v1.y) & 0xFFFF0000u);
        pk.w = (__float_as_uint(v1.z) >> 16) | (__float_as_uint(v1.w) & 0xFFFF0000u);
        *(uint4*)(xbf + (long)blk * 2048 + t * 8) = pk;
        float ssq = v0.x*v0.x + v0.y*v0.y + v0.z*v0.z + v0.w*v0.w
                  + v1.x*v1.x + v1.y*v1.y + v1.z*v1.z + v1.w*v1.w;
        atomicAdd(&xr[lr], ssq);
        __syncthreads();
        if (t < 16) xn[blk * 16 + t] = xr[t];
    } else if (blk < 12628) {
        __shared__ float rowv[2][D];
        __shared__ float red[2][D];
        const int half = t >> 7, tt = t & 127;
        const int row = (blk - 12500) * 2 + half;
        rowv[half][tt] = q[row * D + tt];
        __syncthreads();
        float s = 0.f;
        const float* wr = W + tt * D;
        #pragma unroll 4
        for (int k = 0; k < D; k++) s = fmaf(rowv[half][k], wr[k], s);
        s += bb[tt];
        comb[row * D + tt] = s;
        unsigned ub = __float_as_uint(s);
        unsigned short hv = (unsigned short)((ub + 0x7fffu + ((ub >> 16) & 1u)) >> 16);
        int ksb = tt >> 5, quad = (tt & 31) >> 3, jj = tt & 7;
        int lane = quad * 16 + (row & 15);
        tqsw[(row >> 4) * 2048 + ksb * 512 + lane * 8 + jj] = hv;
        float dd = s - rowv[half][tt];
        red[half][tt] = dd * dd;
        __syncthreads();
        for (int off = 64; off > 0; off >>= 1) { if (tt < off) red[half][tt] += red[half][tt + off]; __syncthreads(); }
        if (tt == 0) atomicAdd(&acc[0], red[half][0]);
    } else if (blk < 12756) {
        const int half = t >> 7, tt = t & 127;
        const int i = (blk - 12628) * 2 + half;
        comb[(256 + i) * D + tt] = X[(long)idx[i] * D + tt];
    } else {
        __shared__ float wred[4];
        const int base = (blk - 12756) * 4096;
        float s = 0.f;
        #pragma unroll 4
        for (int k = 0; k < 16; k++) { float v = W[base + k * 256 + t]; s = fmaf(v, v, s); }
        if (blk == 12756 && t < D) { float v = bb[t]; s = fmaf(v, v, s); }
        #pragma unroll
        for (int off = 32; off > 0; off >>= 1) s += __shfl_down(s, off);
        if ((t & 63) == 0) wred[t >> 6] = s;
        __syncthreads();
        if (t == 0) atomicAdd(&acc[7], wred[0] + wred[1] + wred[2] + wred[3]);
    }
}

// ---- D2 (512x512) + fused 12-bit histogram; 4 waves share one cj stage ----
__global__ void k_d2h(const float* __restrict__ comb, float* __restrict__ D2w,
                      unsigned* __restrict__ hist0)
{
    __shared__ float cj[64][D + 1];
    __shared__ float ci[4][D];
    __shared__ unsigned h[4096];
    const int ib = blockIdx.x, jb = blockIdx.y, t = threadIdx.x;
    const int w = t >> 6, l = t & 63;
    for (int m = t; m < 4096; m += 256) h[m] = 0;
    const int irow = ib * 4 + w;
    ci[w][l] = comb[irow * D + l];
    ci[w][l + 64] = comb[irow * D + l + 64];
    const float4* src = (const float4*)(comb + (jb * 64) * D);
    #pragma unroll
    for (int m = 0; m < 8; m++) {
        int u = m * 256 + t;
        int r = u >> 5, c = u & 31;
        float4 v = src[u];
        cj[r][c * 4 + 0] = v.x; cj[r][c * 4 + 1] = v.y; cj[r][c * 4 + 2] = v.z; cj[r][c * 4 + 3] = v.w;
    }
    __syncthreads();
    float s = 0.f;
    #pragma unroll 4
    for (int k = 0; k < D; k++) { float d = ci[w][k] - cj[l][k]; s = fmaf(d, d, s); }
    D2w[irow * 512 + jb * 64 + l] = s;
    atomicAdd(&h[__float_as_uint(s) >> 20], 1u);
    __syncthreads();
    const int sh = (ib + jb) & 7;
    for (int m = t; m < 4096; m += 256) { unsigned v = h[m]; if (v) atomicAdd(&hist0[m * 8 + sh], v); }
}

// ---- mf0: samples via LDS-staged chunks (blocks 0..255 = one 32-row chunk) + scan0 (block 256) ----
__global__ __launch_bounds__(256) void k_mf0(const unsigned short* __restrict__ tqsw,
    const unsigned short* __restrict__ xbf, const float* __restrict__ xn,
    float* __restrict__ samp, const unsigned* __restrict__ hist0, unsigned* __restrict__ sel)
{
    if (blockIdx.x == 256) {
        __shared__ unsigned part[256];
        const int t = threadIdx.x;
        unsigned s = 0;
        for (int m = 0; m < 16; m++) {
            int b = t * 16 + m;
            #pragma unroll
            for (int sh = 0; sh < 8; sh++) s += hist0[b * 8 + sh];
        }
        part[t] = s;
        __syncthreads();
        if (t == 0) {
            for (int tg = 0; tg < 2; tg++) {
                unsigned r = tg ? 131072u : 131071u;
                int c = 0;
                while (part[c] <= r) { r -= part[c]; c++; }
                int b = c * 16;
                while (true) {
                    unsigned bs = 0;
                    #pragma unroll
                    for (int sh = 0; sh < 8; sh++) bs += hist0[b * 8 + sh];
                    if (bs <= r) { r -= bs; b++; } else break;
                }
                sel[2 * tg] = (unsigned)b; sel[2 * tg + 1] = r;
            }
        }
        return;
    }
    __shared__ unsigned short sb[4096]; // 8 KB chunk
    const int t = threadIdx.x;
    const int w = t >> 6, lane = t & 63;
    const int lr = lane & 15, quad = lane >> 4;
    const int ck = blockIdx.x;
    stage8k(xbf + (long)ck * 4096, sb, w, lane);
    bf16x8 a[4][4];
    #pragma unroll
    for (int i = 0; i < 4; i++)
        #pragma unroll
        for (int ks = 0; ks < 4; ks++)
            a[i][ks] = *(const bf16x8*)(tqsw + (w * 4 + i) * 2048 + ks * 512 + lane * 8);
    __syncthreads();
    #pragma unroll
    for (int tt = 0; tt < 2; tt++) {
        const int r = (ck * 2 + tt) * 16 + lr;
        float xnv = xn[r];
        bf16x8 b[4];
        #pragma unroll
        for (int ks = 0; ks < 4; ks++)
            b[ks] = *(const bf16x8*)(sb + tt * 2048 + ks * 512 + lane * 8);
        f32x4 acc[4];
        #pragma unroll
        for (int i = 0; i < 4; i++) acc[i] = (f32x4){0.f, 0.f, 0.f, 0.f};
        #pragma unroll
        for (int ks = 0; ks < 4; ks++)
            #pragma unroll
            for (int i = 0; i < 4; i++)
                acc[i] = __builtin_amdgcn_mfma_f32_16x16x32_bf16(a[i][ks], b[ks], acc[i], 0, 0, 0);
        #pragma unroll
        for (int i = 0; i < 4; i++)
            #pragma unroll
            for (int reg = 0; reg < 4; reg++) {
                int qq = w * 64 + i * 16 + quad * 4 + reg;
                samp[qq * NS + r] = xnv - 2.f * acc[i][reg];
            }
    }
}

// ---- hist pass1 (blocks 0..255) + per-query sample threshold (blocks 256..511) ----
__global__ void k_h1thr(const float* __restrict__ D2w, unsigned* __restrict__ hist12,
                        const unsigned* __restrict__ sel, const float* __restrict__ samp,
                        float* __restrict__ thr)
{
    __shared__ unsigned buf[8192];
    __shared__ unsigned wred[4];
    const int t = threadIdx.x;
    if (blockIdx.x < 256) {
        for (int m = t; m < 8192; m += 256) buf[m] = 0;
        __syncthreads();
        unsigned p0 = sel[0], p1 = sel[2];
        const int e0 = blockIdx.x * 1024;
        for (int m = 0; m < 4; m++) {
            unsigned key = __float_as_uint(D2w[e0 + m * 256 + t]);
            if ((key >> 20) == p0) atomicAdd(&buf[(key >> 8) & 0xFFFu], 1u);
            if ((key >> 20) == p1) atomicAdd(&buf[4096 + ((key >> 8) & 0xFFFu)], 1u);
        }
        __syncthreads();
        for (int m = t; m < 8192; m += 256) { unsigned v = buf[m]; if (v) atomicAdd(&hist12[m], v); }
    } else {
        const int q = blockIdx.x - 256;
        for (int m = t; m < NS; m += 256) buf[m] = fkey(samp[q * NS + m]);
        __syncthreads();
        unsigned v = 0;
        for (int bit = 31; bit >= 0; bit--) {
            unsigned trial = v | (1u << bit);
            unsigned c = 0;
            for (int m = t; m < NS; m += 256) c += (buf[m] < trial) ? 1u : 0u;
            #pragma unroll
            for (int off = 32; off > 0; off >>= 1) c += __shfl_down(c, off);
            if ((t & 63) == 0) wred[t >> 6] = c;
            __syncthreads();
            unsigned total = wred[0] + wred[1] + wred[2] + wred[3];
            __syncthreads();
            if (total <= (unsigned)(KNN - 1)) v = trial;
        }
        if (t == 0) {
            unsigned orig = (v & 0x80000000u) ? (v ^ 0x80000000u) : ~v;
            thr[q] = __uint_as_float(orig) + SLACK;
        }
    }
}

// ---- hist pass2 with fused local scan1 (block 0 persists sel[4..7]) ----
__global__ void k_hist2s(const float* __restrict__ D2w, unsigned* __restrict__ hist12,
                         unsigned* __restrict__ sel)
{
    __shared__ unsigned h[8192];
    __shared__ unsigned part[256];
    __shared__ unsigned pfx[2];
    __shared__ unsigned rr[2];
    const int t = threadIdx.x;
    for (int tg = 0; tg < 2; tg++) {
        const unsigned* hh = hist12 + tg * 4096;
        unsigned s = 0;
        for (int m = 0; m < 16; m++) s += hh[t * 16 + m];
        part[t] = s;
        __syncthreads();
        if (t == 0) {
            unsigned r = sel[1 + 2 * tg];
            int c = 0;
            while (part[c] <= r) { r -= part[c]; c++; }
            int b = c * 16;
            while (hh[b] <= r) { r -= hh[b]; b++; }
            pfx[tg] = (sel[2 * tg] << 12) | (unsigned)b;
            rr[tg] = r;
        }
        __syncthreads();
    }
    if (blockIdx.x == 0 && t == 0) {
        sel[4] = pfx[0]; sel[5] = rr[0]; sel[6] = pfx[1]; sel[7] = rr[1];
    }
    for (int m = t; m < 8192; m += 256) h[m] = 0;
    __syncthreads();
    unsigned p0 = pfx[0], p1 = pfx[1];
    const int e0 = blockIdx.x * 1024;
    for (int m = 0; m < 4; m++) {
        unsigned key = __float_as_uint(D2w[e0 + m * 256 + t]);
        if ((key >> 8) == p0) atomicAdd(&h[key & 0xFFu], 1u);
        if ((key >> 8) == p1) atomicAdd(&h[4096 + (key & 0xFFu)], 1u);
    }
    __syncthreads();
    unsigned* gp = hist12 + 8192;
    for (int m = t; m < 8192; m += 256) { unsigned v = h[m]; if (v) atomicAdd(&gp[m], v); }
}

// ---- mf1: filter, LDS dbuf staging; candidates -> per-block contiguous lists (NO global atomics)
//      blocks 0..1023 = matmul+filter; 1024..1279 = mmd ----
__global__ __launch_bounds__(256) void k_mf1(const unsigned short* __restrict__ tqsw,
    const unsigned short* __restrict__ xbf, const float* __restrict__ xn,
    const float* __restrict__ thr, unsigned* __restrict__ ebuf, unsigned* __restrict__ bcnt,
    const float* __restrict__ D2w, const unsigned* __restrict__ hist12,
    const unsigned* __restrict__ sel, float* __restrict__ acc)
{
    if (blockIdx.x >= 1024) {
        __shared__ unsigned h2[512];
        __shared__ float gsh;
        __shared__ float part[12];
        const int t = threadIdx.x, w = t >> 6;
        h2[t] = hist12[8192 + t];
        h2[256 + t] = hist12[8192 + 4096 + t];
        __syncthreads();
        if (t == 0) {
            unsigned key[2];
            for (int tg = 0; tg < 2; tg++) {
                unsigned r = sel[5 + 2 * tg];
                const unsigned* hh = h2 + tg * 256;
                int b = 0;
                while (hh[b] <= r) { r -= hh[b]; b++; }
                key[tg] = (sel[4 + 2 * tg] << 8) | (unsigned)b;
            }
            float med = 0.5f * (__uint_as_float(key[0]) + __uint_as_float(key[1]));
            float ssq = 0.5f * med;
            if (ssq < 1e-6f) ssq = 1.0f;
            gsh = 1.0f / (ssq + 1e-8f);
        }
        __syncthreads();
        const float g = gsh;
        float s[3] = {0.f, 0.f, 0.f};
        const int e0 = (blockIdx.x - 1024) * 1024;
        #pragma unroll
        for (int m = 0; m < 4; m++) {
            int e = e0 + m * 256 + t;
            int i = e >> 9, j = e & 511;
            float v = expf(-g * D2w[e]);
            int qd = (i < 256) ? ((j < 256) ? 0 : 2) : ((j < 256) ? 2 : 1);
            s[qd] += v;
        }
        #pragma unroll
        for (int c = 0; c < 3; c++) {
            float x = s[c];
            #pragma unroll
            for (int off = 32; off > 0; off >>= 1) x += __shfl_down(x, off);
            if ((t & 63) == 0) part[w * 3 + c] = x;
        }
        __syncthreads();
        if (t == 0)
            for (int c = 0; c < 3; c++)
                atomicAdd(&acc[2 + c], part[c] + part[3 + c] + part[6 + c] + part[9 + c]);
        return;
    }
    __shared__ unsigned short sb[2][4096]; // double-buffered 8 KB chunks
    __shared__ unsigned lbuf[1024];        // packed (qq<<18)|r candidates
    __shared__ unsigned lcnt;
    __shared__ unsigned gbase;             // running write offset into this block's ebuf list
    const int t = threadIdx.x;
    const int w = t >> 6, lane = t & 63;
    const int lr = lane & 15, quad = lane >> 4;
    unsigned* eb = ebuf + (unsigned)blockIdx.x * EB;
    bf16x8 a[4][4];
    #pragma unroll
    for (int i = 0; i < 4; i++)
        #pragma unroll
        for (int ks = 0; ks < 4; ks++)
            a[i][ks] = *(const bf16x8*)(tqsw + (w * 4 + i) * 2048 + ks * 512 + lane * 8);
    float th_r[4][4];
    #pragma unroll
    for (int i = 0; i < 4; i++)
        #pragma unroll
        for (int reg = 0; reg < 4; reg++)
            th_r[i][reg] = thr[w * 64 + i * 16 + quad * 4 + reg];
    int ck = blockIdx.x;
    int cur = 0;
    if (t == 0) { lcnt = 0; gbase = 0; }
    stage8k(xbf + (long)ck * 4096, sb[0], w, lane);
    __syncthreads();
    while (true) {
        const int ckn = ck + 1024;
        const bool has = ckn < 6250;
        if (has) stage8k(xbf + (long)ckn * 4096, sb[cur ^ 1], w, lane);
        #pragma unroll
        for (int tt = 0; tt < 2; tt++) {
            const int r = (ck * 2 + tt) * 16 + lr;
            float xnv = xn[r];
            bf16x8 b[4];
            #pragma unroll
            for (int ks = 0; ks < 4; ks++)
                b[ks] = *(const bf16x8*)(sb[cur] + tt * 2048 + ks * 512 + lane * 8);
            f32x4 acc4[4];
            #pragma unroll
            for (int i = 0; i < 4; i++) acc4[i] = (f32x4){0.f, 0.f, 0.f, 0.f};
            #pragma unroll
            for (int ks = 0; ks < 4; ks++)
                #pragma unroll
                for (int i = 0; i < 4; i++)
                    acc4[i] = __builtin_amdgcn_mfma_f32_16x16x32_bf16(a[i][ks], b[ks], acc4[i], 0, 0, 0);
            #pragma unroll
            for (int i = 0; i < 4; i++)
                #pragma unroll
                for (int reg = 0; reg < 4; reg++) {
                    float s = xnv - 2.f * acc4[i][reg];
                    if (s <= th_r[i][reg]) {
                        unsigned qq = (unsigned)(w * 64 + i * 16 + quad * 4 + reg);
                        unsigned p = atomicAdd(&lcnt, 1u);
                        if (p < 1024u) lbuf[p] = (qq << 18) | (unsigned)r;
                        else { // overflow fallback: direct contiguous store (rare)
                            unsigned d = gbase + p;
                            if (d < EB) eb[d] = (qq << 18) | (unsigned)r;
                        }
                    }
                }
        }
        __syncthreads(); // publishes lcnt/lbuf; drains prefetch into sb[cur^1]
        unsigned n = lcnt;
        if (!has || n >= 512u) {
            unsigned nf = (n < 1024u) ? n : 1024u;
            unsigned gb = gbase;
            for (unsigned m = t; m < nf; m += 256) {
                unsigned d = gb + m;
                if (d < EB) eb[d] = lbuf[m];
            }
            __syncthreads();
            if (t == 0) { gbase = gb + n; lcnt = 0; }
            __syncthreads();
        }
        if (!has) break;
        ck = ckn; cur ^= 1;
    }
    if (t == 0) bcnt[blockIdx.x] = (gbase < EB) ? gbase : EB;
}

// ---- scatter: per-block lists -> per-query arrays; aggregated atomics (1 per block-group x query) ----
__global__ __launch_bounds__(256) void k_scat(const unsigned* __restrict__ ebuf,
    const unsigned* __restrict__ bcnt, int* __restrict__ cand_i, unsigned* __restrict__ cnt)
{
    __shared__ unsigned hist[256];
    __shared__ unsigned startp[256];
    const int t = threadIdx.x;
    const int b0 = blockIdx.x * 8;   // 128 blocks x 8 lists = 1024 lists
    hist[t] = 0;
    __syncthreads();
    for (int b = b0; b < b0 + 8; b++) {
        unsigned n = bcnt[b];
        const unsigned* e = ebuf + (unsigned)b * EB;
        for (unsigned m = t; m < n; m += 256)
            atomicAdd(&hist[e[m] >> 18], 1u);
    }
    __syncthreads();
    unsigned c = hist[t];
    if (c) {
        unsigned base = atomicAdd(&cnt[t * 16], c);
        startp[t] = ((unsigned)t << 13) + base;
    }
    __syncthreads();
    for (int b = b0; b < b0 + 8; b++) {
        unsigned n = bcnt[b];
        const unsigned* e = ebuf + (unsigned)b * EB;
        for (unsigned m = t; m < n; m += 256) {
            unsigned ent = e[m];
            unsigned qq = ent >> 18;
            unsigned pos = atomicAdd(&startp[qq], 1u);
            if (pos < ((qq + 1u) << 13)) cand_i[pos] = (int)(ent & 0x3FFFFu);
        }
    }
}

// ---- exact f32 rescore of candidates (16 splits per query for co-residency) ----
__global__ void k_rescore(const float* __restrict__ comb, const float* __restrict__ X,
                          const float* __restrict__ xn, const int* __restrict__ cand_i,
                          const unsigned* __restrict__ cnt, unsigned* __restrict__ ksg)
{
    __shared__ float qrow[D];
    const int q = blockIdx.x, sp = blockIdx.y, t = threadIdx.x;
    if (t < D) qrow[t] = comb[q * D + t];
    __syncthreads();
    unsigned nn = cnt[q * 16];
    const int n = (nn < (unsigned)CAP) ? (int)nn : CAP;
    const int g = t >> 3, j = t & 7;
    for (int m = sp * 32 + g; m < n; m += 512) {
        int r = cand_i[q * CAP + m];
        const float4* xr = (const float4*)(X + (long)r * D);
        float s = 0.f;
        #pragma unroll
        for (int p = 0; p < 4; p++) {
            float4 xv = xr[j * 4 + p];
            float4 qv = *(const float4*)&qrow[(j * 4 + p) * 4];
            s = fmaf(xv.x, qv.x, fmaf(xv.y, qv.y, fmaf(xv.z, qv.z, fmaf(xv.w, qv.w, s))));
        }
        s += __shfl_down(s, 4); s += __shfl_down(s, 2); s += __shfl_down(s, 1);
        if (j == 0) ksg[q * CAP + m] = fkey(xn[r] - 2.f * s);
    }
}

// ---- per-query: top-50 from precomputed keys -> l2 -> softmax -> union KL ----
__global__ void k_post2(const float* __restrict__ comb, const float* __restrict__ X,
                        const int* __restrict__ cand_i, const unsigned* __restrict__ cnt,
                        const unsigned* __restrict__ ksg, const int* __restrict__ pri,
                        const float* __restrict__ prw, const int* __restrict__ qix,
                        float* __restrict__ acc)
{
    __shared__ unsigned ks[CAP];
    __shared__ float qrow[D];
    __shared__ unsigned wred[4];
    __shared__ unsigned wpos, eqn;
    __shared__ int eq[64];
    __shared__ int pidx[KNN];
    __shared__ float l2s[KNN];
    __shared__ float pw[KNN];
    __shared__ int ci[100];
    __shared__ float pwv[50], qwv[50];
    __shared__ float pterm[100], qterm[100], kterm[100];
    __shared__ float Sp, Sq;
    const int q = blockIdx.x, t = threadIdx.x;
    if (t < D) qrow[t] = comb[q * D + t];
    if (t == 0) { wpos = 0; eqn = 0; }
    unsigned nn = cnt[q * 16];
    const int n = (nn < (unsigned)CAP) ? (int)nn : CAP;
    for (int m = t; m < n; m += 256) ks[m] = ksg[q * CAP + m];
    __syncthreads();
    int kk = KNN - 1; if (kk > n - 1) kk = n - 1;
    unsigned v = 0;
    for (int bit = 31; bit >= 0; bit--) {
        unsigned trial = v | (1u << bit);
        unsigned c = 0;
        for (int m = t; m < n; m += 256) c += (ks[m] < trial) ? 1u : 0u;
        #pragma unroll
        for (int off = 32; off > 0; off >>= 1) c += __shfl_down(c, off);
        if ((t & 63) == 0) wred[t >> 6] = c;
        __syncthreads();
        unsigned total = wred[0] + wred[1] + wred[2] + wred[3];
        __syncthreads();
        if (total <= (unsigned)kk) v = trial;
    }
    for (int m = t; m < n; m += 256) {
        if (ks[m] < v) {
            unsigned p = atomicAdd(&wpos, 1u);
            pidx[p] = cand_i[q * CAP + m];
        } else if (ks[m] == v) {
            unsigned p = atomicAdd(&eqn, 1u);
            if (p < 64) eq[p] = cand_i[q * CAP + m];
        }
    }
    __syncthreads();
    if (t == 0) {
        int c1 = (int)wpos, need = KNN - c1;
        int ne = (eqn < 64u) ? (int)eqn : 64;
        for (int a = 0; a < ne; a++)
            for (int b2 = a + 1; b2 < ne; b2++)
                if (eq[b2] < eq[a]) { int tmp = eq[a]; eq[a] = eq[b2]; eq[b2] = tmp; }
        for (int a = 0; a < need && a < ne; a++) pidx[c1 + a] = eq[a];
    }
    __syncthreads();
    const int g = t >> 3, j = t & 7;
    for (int nb = g; nb < KNN; nb += 32) {
        long r = pidx[nb];
        const float4* xr = (const float4*)(X + r * D);
        float s = 0.f;
        #pragma unroll
        for (int p = 0; p < 4; p++) {
            float4 xv = xr[j * 4 + p];
            float4 qv = *(const float4*)&qrow[(j * 4 + p) * 4];
            float d0 = qv.x - xv.x, d1 = qv.y - xv.y, d2 = qv.z - xv.z, d3 = qv.w - xv.w;
            s += d0 * d0 + d1 * d1 + d2 * d2 + d3 * d3;
        }
        s += __shfl_down(s, 4); s += __shfl_down(s, 2); s += __shfl_down(s, 1);
        if (j == 0) l2s[nb] = s;
    }
    int qi = qix[q];
    if (t >= 128 && t < 178) { int k = t - 128; ci[k] = pri[qi * 50 + k]; pwv[k] = prw[qi * 50 + k]; }
    __syncthreads();
    if (t < 64) {
        float logit = (t < KNN) ? (-l2s[t] * 10.0f) : -3.4e38f; // 1/tau = 10
        float m = logit;
        #pragma unroll
        for (int off = 32; off > 0; off >>= 1) m = fmaxf(m, __shfl_down(m, off));
        m = __shfl(m, 0);
        float e = (t < KNN) ? expf(logit - m) : 0.f;
        float ss = e;
        #pragma unroll
        for (int off = 32; off > 0; off >>= 1) ss += __shfl_down(ss, off);
        ss = __shfl(ss, 0);
        if (t < KNN) pw[t] = e / ss;
    }
    __syncthreads();
    if (t < 50) { ci[50 + t] = pidx[t]; qwv[t] = pw[t]; }
    __syncthreads();
    float pc = 0.f, qc = 0.f, mult = 0.f;
    if (t < 100) {
        int c = ci[t];
        float pr = 0.f, qr = 0.f;
        for (int k = 0; k < 50; k++) {
            bool m1 = (c == ci[k]); bool m2 = (c == ci[50 + k]);
            mult += (m1 ? 1.f : 0.f) + (m2 ? 1.f : 0.f);
            pr += m1 ? pwv[k] : 0.f;
            qr += m2 ? qwv[k] : 0.f;
        }
        pc = fmaxf(pr, 1e-8f); qc = fmaxf(qr, 1e-8f);
        pterm[t] = pc / mult; qterm[t] = qc / mult;
    }
    __syncthreads();
    if (t == 0) { float a = 0.f, b2 = 0.f; for (int m = 0; m < 100; m++) { a += pterm[m]; b2 += qterm[m]; } Sp = a; Sq = b2; }
    __syncthreads();
    if (t < 100) {
        float p = pc / Sp, qq2 = qc / Sq;
        kterm[t] = (p * (logf(p) - logf(qq2))) / mult;
    }
    __syncthreads();
    if (t == 0) { float s = 0.f; for (int m = 0; m < 100; m++) s += kterm[m]; atomicAdd(&acc[1], s); }
}

// ---- final assembly (reg precomputed in phase1) ----
__global__ void k_final(const float* __restrict__ acc, float* __restrict__ out)
{
    if (threadIdx.x == 0) {
        float reg = 0.5f * acc[7];
        float kxx = acc[2] / 65536.f, kyy = acc[3] / 65536.f, kxy = acc[4] / 131072.f;
        float ld = fmaxf(kxx + kyy - 2.f * kxy, 0.f);
        float lknn = acc[1] / 256.f;
        float lanc = acc[0] / 256.f;
        out[0] = ld + lknn + 1e-4f * reg + lanc;
        out[1] = ld; out[2] = lknn; out[3] = lanc;
    }
}

extern "C" void kernel_launch(void* const* d_in, const int* in_sizes, int n_in,
                              void* d_out, int out_size, void* d_ws, size_t ws_size,
                              hipStream_t stream)
{
    (void)in_sizes; (void)n_in; (void)out_size; (void)ws_size;
    const float* q   = (const float*)d_in[0];
    const float* X   = (const float*)d_in[1];
    const float* W   = (const float*)d_in[2];
    const float* bb  = (const float*)d_in[3];
    const float* prw = (const float*)d_in[4];
    const int*   pri = (const int*)d_in[5];
    const int*   qix = (const int*)d_in[6];
    const int*   idx = (const int*)d_in[7];
    float* out = (float*)d_out;
    char* ws = (char*)d_ws;
    float*    acc   = (float*)(ws + OFF_ACC);
    unsigned* sel   = (unsigned*)(ws + OFF_SEL);
    unsigned* cnt   = (unsigned*)(ws + OFF_CNT);
    unsigned* hist0 = (unsigned*)(ws + OFF_HIST0);
    unsigned* hist12= (unsigned*)(ws + OFF_HIST12);
    float*    comb  = (float*)(ws + OFF_COMB);
    float*    D2w   = (float*)(ws + OFF_D2);
    float*    xn    = (float*)(ws + OFF_XN);
    float*    samp  = (float*)(ws + OFF_SAMP);
    float*    thr   = (float*)(ws + OFF_THR);
    int*      cix   = (int*)(ws + OFF_CANDI);
    unsigned* ksg   = (unsigned*)(ws + OFF_KSG);
    unsigned* ebuf  = (unsigned*)(ws + OFF_EBUF);   // aliases samp (dead after k_h1thr)
    unsigned* bcnt  = (unsigned*)(ws + OFF_BCNT);   // aliases ksg head (written after k_scat)
    unsigned short* tqsw = (unsigned short*)(ws + OFF_TQSW);
    unsigned short* xbf  = (unsigned short*)(ws + OFF_XBF);

    hipMemsetAsync(ws, 0, MEMSET_BYTES, stream);
    hipLaunchKernelGGL(k_phase1,  dim3(12760),   dim3(256), 0, stream, q, X, W, bb, idx, comb, tqsw, xbf, xn, acc);
    hipLaunchKernelGGL(k_d2h,     dim3(128, 8),  dim3(256), 0, stream, comb, D2w, hist0);
    hipLaunchKernelGGL(k_mf0,     dim3(257),     dim3(256), 0, stream, tqsw, xbf, xn, samp, hist0, sel);
    hipLaunchKernelGGL(k_h1thr,   dim3(512),     dim3(256), 0, stream, D2w, hist12, sel, samp, thr);
    hipLaunchKernelGGL(k_hist2s,  dim3(256),     dim3(256), 0, stream, D2w, hist12, sel);
    hipLaunchKernelGGL(k_mf1,     dim3(1280),    dim3(256), 0, stream, tqsw, xbf, xn, thr, ebuf, bcnt, D2w, hist12, sel, acc);
    hipLaunchKernelGGL(k_scat,    dim3(128),     dim3(256), 0, stream, ebuf, bcnt, cix, cnt);
    hipLaunchKernelGGL(k_rescore, dim3(256, 16), dim3(256), 0, stream, comb, X, xn, cix, cnt, ksg);
    hipLaunchKernelGGL(k_post2,   dim3(256),     dim3(256), 0, stream, comb, X, cix, cnt, ksg, pri, prw, qix, acc);
    hipLaunchKernelGGL(k_final,   dim3(1),       dim3(64),  0, stream, acc, out);
}